// Round 9
// baseline (2965.169 us; speedup 1.0000x reference)
//
#include <hip/hip_runtime.h>
#include <hip/hip_cooperative_groups.h>

namespace cg = cooperative_groups;

#define NB 1024   // batch
#define TT 32     // encoder length
#define DIN 256   // input dim
#define HD 256    // hidden dim
#define NC 38     // classes
#define NSTEP 26  // decode steps

typedef unsigned short ushort_t;
typedef __attribute__((ext_vector_type(8))) short bf16x8;
typedef __attribute__((ext_vector_type(8))) unsigned short us8;
typedef __attribute__((ext_vector_type(4))) float f32x4;

#define GLOAD_LDS16(g, l) \
  __builtin_amdgcn_global_load_lds((const __attribute__((address_space(1))) unsigned int*)(g), \
                                   (__attribute__((address_space(3))) unsigned int*)(l), 16, 0, 0)

__device__ __forceinline__ unsigned short f2bf(float x) {
    union { float f; unsigned u; } v; v.f = x;
    unsigned r = v.u + 0x7fff + ((v.u >> 16) & 1);   // RNE
    return (unsigned short)(r >> 16);
}
__device__ __forceinline__ float bf2f(unsigned short h) {
    union { unsigned u; float f; } v; v.u = ((unsigned)h) << 16;
    return v.f;
}
__device__ __forceinline__ float fast_tanh(float x) {
    float xc = fminf(fmaxf(x, -15.f), 15.f);
    float z = __expf(2.f * xc);
    return (z - 1.f) * __builtin_amdgcn_rcpf(z + 1.f);
}
__device__ __forceinline__ float fast_sig(float x) {
    return __builtin_amdgcn_rcpf(1.f + __expf(-x));
}

// ---------------------------------------------------------------------------
// prep_all: 3584 blocks (unchanged, proven).
// ---------------------------------------------------------------------------
__global__ __launch_bounds__(256) void prep_all(
    const float* __restrict__ w_ih, const float* __restrict__ w_hh,
    const float* __restrict__ w_i2h, const float* __restrict__ w_h2h,
    const float* __restrict__ enc,
    ushort_t* __restrict__ B2g, ushort_t* __restrict__ B2i,
    ushort_t* __restrict__ w2hb, ushort_t* __restrict__ encA2)
{
    const int bid = blockIdx.x, tid = threadIdx.x;
    if (bid < 1024) {
        int j = bid;
        for (int k = tid; k < 512; k += 256) {
            float x = (k < 256) ? w_ih[(size_t)j * 294 + k] : w_hh[(size_t)j * 256 + (k - 256)];
            unsigned short hi = f2bf(x);
            unsigned short lo = f2bf(x - bf2f(hi));
            size_t r = (size_t)j * 1536;
            B2g[r + k] = hi; B2g[r + 512 + k] = lo; B2g[r + 1024 + k] = hi;
        }
    } else if (bid < 1280) {
        int n = bid - 1024;
        float x = w_i2h[(size_t)n * 256 + tid];
        unsigned short hi = f2bf(x);
        unsigned short lo = f2bf(x - bf2f(hi));
        size_t r = (size_t)n * 768;
        B2i[r + tid] = hi; B2i[r + 256 + tid] = lo; B2i[r + 512 + tid] = hi;
    } else if (bid < 1536) {
        int j = bid - 1280;
        w2hb[(size_t)j * 256 + tid] = f2bf(w_h2h[(size_t)j * 256 + tid]);
    } else {
        int base = (bid - 1536) * 16;
#pragma unroll
        for (int rr = 0; rr < 16; rr++) {
            size_t row = base + rr;
            float x = enc[row * 256 + tid];
            unsigned short hi = f2bf(x);
            unsigned short lo = f2bf(x - bf2f(hi));
            encA2[row * 512 + tid] = hi;
            encA2[row * 512 + 256 + tid] = lo;
        }
    }
}

// ---------------------------------------------------------------------------
// hproj_pipe: Hb[m][n] = bf16( sum_k enc[m][k]*w_i2h[n][k] )   (proven)
// ---------------------------------------------------------------------------
__global__ __launch_bounds__(256) void hproj_pipe(
    const ushort_t* __restrict__ encA2, const ushort_t* __restrict__ B2i,
    ushort_t* __restrict__ Hb)
{
    __shared__ ushort_t lA[2][64 * 128];
    __shared__ ushort_t lB[2][64 * 128];

    const int tid = threadIdx.x;
    const int lane = tid & 63, wid = tid >> 6;
    const int wm = wid >> 1, wn = wid & 1;
    const int m0 = blockIdx.x * 64, n0 = blockIdx.y * 64;

    f32x4 acc[2][2];
    const f32x4 fz = {0.f, 0.f, 0.f, 0.f};
    acc[0][0] = fz; acc[0][1] = fz; acc[1][0] = fz; acc[1][1] = fz;

    auto stage = [&](int t, int buf) {
#pragma unroll
        for (int i = 0; i < 4; i++) {
            int cpos = tid + i * 256;
            int m = cpos >> 4, p = cpos & 15;
            int g = p ^ (m & 7);
            int vk = t * 128 + g * 8;
            int acol = (vk < 256) ? vk : vk - 256;
            GLOAD_LDS16(&encA2[(size_t)(m0 + m) * 512 + acol], &lA[buf][cpos * 8]);
        }
#pragma unroll
        for (int i = 0; i < 4; i++) {
            int cpos = tid + i * 256;
            int n = cpos >> 4, p = cpos & 15;
            int g = p ^ (n & 7);
            GLOAD_LDS16(&B2i[(size_t)(n0 + n) * 768 + t * 128 + g * 8], &lB[buf][cpos * 8]);
        }
    };

    stage(0, 0);
    stage(1, 1);

    for (int t = 0; t < 6; t++) {
        int cur = t & 1;
        if (t < 5) asm volatile("s_waitcnt vmcnt(8)" ::: "memory");
        else       asm volatile("s_waitcnt vmcnt(0)" ::: "memory");
        __syncthreads();
#pragma unroll
        for (int kk = 0; kk < 4; kk++) {
            int g = kk * 4 + (lane >> 4);
            bf16x8 af[2], bfr[2];
#pragma unroll
            for (int mi = 0; mi < 2; mi++) {
                int m = wm * 32 + mi * 16 + (lane & 15);
                af[mi] = *(const bf16x8*)&lA[cur][m * 128 + ((g ^ (m & 7)) << 3)];
            }
#pragma unroll
            for (int ni = 0; ni < 2; ni++) {
                int n = wn * 32 + ni * 16 + (lane & 15);
                bfr[ni] = *(const bf16x8*)&lB[cur][n * 128 + ((g ^ (n & 7)) << 3)];
            }
#pragma unroll
            for (int mi = 0; mi < 2; mi++)
#pragma unroll
                for (int ni = 0; ni < 2; ni++)
                    acc[mi][ni] = __builtin_amdgcn_mfma_f32_16x16x32_bf16(af[mi], bfr[ni], acc[mi][ni], 0, 0, 0);
        }
        __syncthreads();
        if (t + 2 < 6) stage(t + 2, cur);
    }

    const int r4 = (lane >> 4) * 4;
#pragma unroll
    for (int mi = 0; mi < 2; mi++)
#pragma unroll
        for (int r = 0; r < 4; r++) {
            size_t row = m0 + wm * 32 + mi * 16 + r4 + r;
#pragma unroll
            for (int ni = 0; ni < 2; ni++) {
                int col = n0 + wn * 32 + ni * 16 + (lane & 15);
                Hb[row * 256 + col] = f2bf(acc[mi][ni][r]);
            }
        }
}

// ---------------------------------------------------------------------------
// decode_loop: 26-step loop, cooperative.  256 blocks x 512 threads,
// 1 block/CU (guaranteed launchable).  Block owns batch rows b0..b0+3
// (Hb + enc slices REGISTER-cached; c in registers) and gates tile 64x64
// (n-panel pinned to XCD blk&7: B2g slice 384 KB L2-resident).
// ---------------------------------------------------------------------------
__global__ __launch_bounds__(512, 2) void decode_loop(
    const ushort_t* __restrict__ Hb, const ushort_t* __restrict__ encA2,
    const ushort_t* __restrict__ B2g, const ushort_t* __restrict__ w2hb,
    const float* __restrict__ b_h2h,
    const float* __restrict__ w_gen, const float* __restrict__ b_gen,
    const float* __restrict__ w_score,
    const float* __restrict__ b_ih, const float* __restrict__ b_hh,
    const float* __restrict__ w_ih, const int* __restrict__ text,
    ushort_t* __restrict__ A2, float* __restrict__ gates,
    float* __restrict__ probs)
{
    cg::grid_group grid = cg::this_grid();

    __shared__ ushort_t lA[2][64 * 128];   // 32 KB (attn scratch aliases this)
    __shared__ ushort_t lB[2][64 * 128];   // 32 KB
    __shared__ float wssh[256];            // persistent

    float* hsh  = (float*)&lA[0][0];       // [4][256]  4 KB
    float* hpsh = hsh + 1024;              // [4][256]  4 KB
    float* esh  = hpsh + 1024;             // [4][32]   512 B
    float* psh  = esh + 128;               // [4][4][256] 16 KB   (24.5 KB < 32 KB)

    const int tid = threadIdx.x;
    const int blk = blockIdx.x;
    const int b0 = blk * 4;                       // attention rows
    const int m0g = (blk >> 4) * 64;              // gates tile
    const int n0g = (blk & 15) * 64;
    const int lane = tid & 63, wid = tid >> 6;
    const int wm = wid >> 2, wn = wid & 3;        // GEMM: 2x4 waves of 32x16
    const f32x4 fz = {0.f, 0.f, 0.f, 0.f};

    // ---- prologue ----
    if (tid < 256) wssh[tid] = w_score[tid];
    float creg0 = 0.f, creg1 = 0.f;
#pragma unroll
    for (int it = 0; it < 2; it++) {
        int idx = tid + it * 512;
        int bl = idx >> 8, hh = idx & 255;
        A2[(size_t)(b0 + bl) * 1024 + 256 + hh] = 0;
        A2[(size_t)(b0 + bl) * 1024 + 768 + hh] = 0;
    }

    // Hb slice -> regs. scores mapping: bl=tid>>7, t=(tid>>2)&31, q=tid&3;
    // thread holds d = q*64 .. q*64+64 of row (b0+bl, t).
    us8 hb[8];
    {
        int bl = tid >> 7, t = (tid >> 2) & 31, q = tid & 3;
        const ushort_t* hr = &Hb[((size_t)(b0 + bl) * TT + t) * HD + q * 64];
#pragma unroll
        for (int j = 0; j < 8; j++) hb[j] = *(const us8*)&hr[j * 8];
    }
    // enc slice (bf16 hi from encA2) -> regs. ctx mapping: bl=tid>>7,
    // tg=(tid>>5)&3, dg=tid&31; thread holds t = tg*8+tt, d = dg*8..+8.
    us8 eb[8];
    {
        int bl = tid >> 7, tg = (tid >> 5) & 3, dg = tid & 31;
#pragma unroll
        for (int tt = 0; tt < 8; tt++)
            eb[tt] = *(const us8*)&encA2[((size_t)(b0 + bl) * TT + tg * 8 + tt) * 512 + dg * 8];
    }

    for (int s = 0; s <= NSTEP; s++) {
        // ---- LSTM(s-1) + probs(s-1) ----
        if (s > 0) {
#pragma unroll
            for (int it = 0; it < 2; it++) {
                int idx = tid + it * 512;
                int bl = idx >> 8, hh = idx & 255;
                int b = b0 + bl;
                const float* g = &gates[(size_t)b * 1024];
                float gi = g[hh];
                float gf = g[256 + hh];
                float gg = g[512 + hh];
                float go = g[768 + hh];
                float cv = (it == 0) ? creg0 : creg1;
                float cn = fast_sig(gf) * cv + fast_sig(gi) * fast_tanh(gg);
                float hn = fast_sig(go) * fast_tanh(cn);
                if (it == 0) creg0 = cn; else creg1 = cn;
                hsh[bl * 256 + hh] = hn;
                if (s < NSTEP) {
                    unsigned short hi_ = f2bf(hn);
                    A2[(size_t)b * 1024 + 256 + hh] = hi_;
                    A2[(size_t)b * 1024 + 768 + hh] = f2bf(hn - bf2f(hi_));
                }
            }
            __syncthreads();
            {
                int bl = tid >> 7, j = tid & 127;
                if (j < NC) {
                    float sacc = b_gen[j];
                    const float* wg = &w_gen[(size_t)j * HD];
                    const float* hv = &hsh[bl * 256];
                    for (int d = 0; d < HD; d += 4) {
                        float4 wv = *(const float4*)&wg[d];
                        float4 hq = *(const float4*)&hv[d];
                        sacc += wv.x * hq.x + wv.y * hq.y + wv.z * hq.z + wv.w * hq.w;
                    }
                    probs[((size_t)(b0 + bl) * NSTEP + (s - 1)) * NC + j] = sacc;
                }
            }
        } else {
#pragma unroll
            for (int it = 0; it < 2; it++) {
                int idx = tid + it * 512;
                hsh[idx] = 0.f;
            }
            __syncthreads();
        }
        if (s == NSTEP) break;

        // ---- hp[b][j] = dot(w2hb[j], h[b]) + b_h2h[j] (2 rows/thread) ----
        {
            int j = tid & 255, hf = tid >> 8;
            float a0 = 0.f, a1 = 0.f;
            const ushort_t* wr = &w2hb[(size_t)j * 256];
            const float* h0 = &hsh[(hf * 2 + 0) * 256];
            const float* h1 = &hsh[(hf * 2 + 1) * 256];
#pragma unroll 4
            for (int d = 0; d < 256; d += 8) {
                us8 wv = *(const us8*)&wr[d];
#pragma unroll
                for (int k = 0; k < 8; k++) {
                    float w = bf2f(wv[k]);
                    a0 += w * h0[d + k];
                    a1 += w * h1[d + k];
                }
            }
            float bb = b_h2h[j];
            hpsh[(hf * 2 + 0) * 256 + j] = a0 + bb;
            hpsh[(hf * 2 + 1) * 256 + j] = a1 + bb;
        }
        __syncthreads();

        // ---- scores from register Hb slice ----
        {
            int bl = tid >> 7, t = (tid >> 2) & 31, q = tid & 3;
            const float* hp = &hpsh[bl * 256 + q * 64];
            const float* wp = &wssh[q * 64];
            float e = 0.f;
#pragma unroll
            for (int j = 0; j < 8; j++) {
                us8 hv = hb[j];
                float4 p0 = *(const float4*)&hp[j * 8];
                float4 p1 = *(const float4*)&hp[j * 8 + 4];
                float4 w0 = *(const float4*)&wp[j * 8];
                float4 w1 = *(const float4*)&wp[j * 8 + 4];
                e += w0.x * fast_tanh(bf2f(hv[0]) + p0.x);
                e += w0.y * fast_tanh(bf2f(hv[1]) + p0.y);
                e += w0.z * fast_tanh(bf2f(hv[2]) + p0.z);
                e += w0.w * fast_tanh(bf2f(hv[3]) + p0.w);
                e += w1.x * fast_tanh(bf2f(hv[4]) + p1.x);
                e += w1.y * fast_tanh(bf2f(hv[5]) + p1.y);
                e += w1.z * fast_tanh(bf2f(hv[6]) + p1.z);
                e += w1.w * fast_tanh(bf2f(hv[7]) + p1.w);
            }
            e += __shfl_xor(e, 1);
            e += __shfl_xor(e, 2);
            if (q == 0) esh[bl * 32 + t] = e;
        }
        __syncthreads();

        // ---- softmax over 32 t, 4 rows on 32-lane groups ----
        if (tid < 128) {
            int bl = tid >> 5, l = tid & 31;
            float v = esh[bl * 32 + l];
            float m = v;
#pragma unroll
            for (int o = 16; o > 0; o >>= 1) m = fmaxf(m, __shfl_xor(m, o));
            float p = __expf(v - m);
            float ssum = p;
#pragma unroll
            for (int o = 16; o > 0; o >>= 1) ssum += __shfl_xor(ssum, o);
            esh[bl * 32 + l] = p * __builtin_amdgcn_rcpf(ssum);
        }
        __syncthreads();

        // ---- context from register enc slice ----
        {
            int bl = tid >> 7, tg = (tid >> 5) & 3, dg = tid & 31;
            float pp[8] = {0.f, 0.f, 0.f, 0.f, 0.f, 0.f, 0.f, 0.f};
#pragma unroll
            for (int tt = 0; tt < 8; tt++) {
                float a = esh[bl * 32 + tg * 8 + tt];
                us8 ev = eb[tt];
#pragma unroll
                for (int k = 0; k < 8; k++) pp[k] += a * bf2f(ev[k]);
            }
#pragma unroll
            for (int k = 0; k < 8; k++)
                psh[(bl * 4 + tg) * 256 + dg * 8 + k] = pp[k];
        }
        __syncthreads();
#pragma unroll
        for (int it = 0; it < 2; it++) {
            int idx = tid + it * 512;
            int bl = idx >> 8, d = idx & 255;
            float a = psh[(bl * 4 + 0) * 256 + d] + psh[(bl * 4 + 1) * 256 + d]
                    + psh[(bl * 4 + 2) * 256 + d] + psh[(bl * 4 + 3) * 256 + d];
            unsigned short hi_ = f2bf(a);
            A2[(size_t)(b0 + bl) * 1024 + d] = hi_;
            A2[(size_t)(b0 + bl) * 1024 + 512 + d] = f2bf(a - bf2f(hi_));
        }

        grid.sync();

        // ---- gates GEMM: tile 64x64, virtual K=1536, dbuf + counted vmcnt ----
        {
            auto stage = [&](int t, int buf) {
#pragma unroll
                for (int i = 0; i < 2; i++) {
                    int cpos = tid + i * 512;
                    int m = cpos >> 4, p = cpos & 15;
                    int g = p ^ (m & 7);
                    int vk = t * 128 + g * 8;
                    int acol = (vk < 512) ? vk : vk - 512;
                    GLOAD_LDS16(&A2[(size_t)(m0g + m) * 1024 + acol], &lA[buf][cpos * 8]);
                }
#pragma unroll
                for (int i = 0; i < 2; i++) {
                    int cpos = tid + i * 512;
                    int n = cpos >> 4, p = cpos & 15;
                    int g = p ^ (n & 7);
                    GLOAD_LDS16(&B2g[(size_t)(n0g + n) * 1536 + t * 128 + g * 8], &lB[buf][cpos * 8]);
                }
            };

            f32x4 acc0 = fz, acc1 = fz;    // mi = 0,1
            stage(0, 0);
            stage(1, 1);

            for (int t = 0; t < 12; t++) {
                int cur = t & 1;
                if (t < 11) asm volatile("s_waitcnt vmcnt(4)" ::: "memory");
                else        asm volatile("s_waitcnt vmcnt(0)" ::: "memory");
                __syncthreads();
                {
                    int n = wn * 16 + (lane & 15);
                    int mA = wm * 32 + (lane & 15);
#pragma unroll
                    for (int kk = 0; kk < 4; kk++) {
                        int gk = kk * 4 + (lane >> 4);
                        bf16x8 bq = *(const bf16x8*)&lB[cur][n * 128 + ((gk ^ (n & 7)) << 3)];
                        bf16x8 a0 = *(const bf16x8*)&lA[cur][mA * 128 + ((gk ^ (mA & 7)) << 3)];
                        bf16x8 a1 = *(const bf16x8*)&lA[cur][(mA + 16) * 128 + ((gk ^ ((mA + 16) & 7)) << 3)];
                        acc0 = __builtin_amdgcn_mfma_f32_16x16x32_bf16(a0, bq, acc0, 0, 0, 0);
                        acc1 = __builtin_amdgcn_mfma_f32_16x16x32_bf16(a1, bq, acc1, 0, 0, 0);
                    }
                }
                __syncthreads();
                if (t + 2 < 12) stage(t + 2, cur);
            }

            {
                int colg = n0g + wn * 16 + (lane & 15);
                float bsum = b_ih[colg] + b_hh[colg];
                const float* wcol = &w_ih[(size_t)colg * 294 + 256];
                int r4 = (lane >> 4) * 4;
#pragma unroll
                for (int r = 0; r < 4; r++) {
                    int row = m0g + wm * 32 + r4 + r;
                    int cl = text[row * NSTEP + s];
                    gates[(size_t)row * 1024 + colg] = acc0[r] + bsum + wcol[cl];
                }
#pragma unroll
                for (int r = 0; r < 4; r++) {
                    int row = m0g + wm * 32 + 16 + r4 + r;
                    int cl = text[row * NSTEP + s];
                    gates[(size_t)row * 1024 + colg] = acc1[r] + bsum + wcol[cl];
                }
            }
        }

        grid.sync();
    }
}

// ---------------------------------------------------------------------------
extern "C" void kernel_launch(void* const* d_in, const int* in_sizes, int n_in,
                              void* d_out, int out_size, void* d_ws, size_t ws_size,
                              hipStream_t stream)
{
    const float* enc     = (const float*)d_in[0];
    const int*   text    = (const int*)d_in[1];
    const float* w_i2h   = (const float*)d_in[4];
    const float* w_h2h   = (const float*)d_in[5];
    const float* b_h2h   = (const float*)d_in[6];
    const float* w_score = (const float*)d_in[7];
    const float* w_ih    = (const float*)d_in[8];
    const float* w_hh    = (const float*)d_in[9];
    const float* b_ih    = (const float*)d_in[10];
    const float* b_hh    = (const float*)d_in[11];
    const float* w_gen   = (const float*)d_in[12];
    const float* b_gen   = (const float*)d_in[13];
    float* out = (float*)d_out;

    const size_t MB = 1024 * 1024;
    char* ws = (char*)d_ws;
    ushort_t* Hb    = (ushort_t*)ws;                          // 16 MB  [0,16)
    ushort_t* B2g   = (ushort_t*)(ws + 16 * MB);              // 3 MB   [16,19)
    ushort_t* B2i   = (ushort_t*)(ws + 19 * MB);              // 384 KB
    ushort_t* w2hb  = (ushort_t*)(ws + 19 * MB + 512 * 1024); // 128 KB
    ushort_t* A2    = (ushort_t*)(ws + 21 * MB);              // 2 MB   [21,23)
    float*    gates = (float*)(ws + 23 * MB);                 // 4 MB   [23,27)
    ushort_t* encA2 = (ushort_t*)(ws + 27 * MB);              // 32 MB  [27,59)

    prep_all<<<3584, 256, 0, stream>>>(w_ih, w_hh, w_i2h, w_h2h, enc,
                                       B2g, B2i, w2hb, encA2);
    hproj_pipe<<<dim3(512, 4), 256, 0, stream>>>(encA2, B2i, Hb);

    void* kargs[] = {
        (void*)&Hb, (void*)&encA2, (void*)&B2g, (void*)&w2hb, (void*)&b_h2h,
        (void*)&w_gen, (void*)&b_gen, (void*)&w_score,
        (void*)&b_ih, (void*)&b_hh, (void*)&w_ih, (void*)&text,
        (void*)&A2, (void*)&gates, (void*)&out
    };
    hipLaunchCooperativeKernel((const void*)decode_loop, dim3(256), dim3(512),
                               kargs, 0, stream);
}

// Round 10
// 1166.728 us; speedup vs baseline: 2.5414x; 2.5414x over previous
//
#include <hip/hip_runtime.h>

#define NB 1024   // batch
#define TT 32     // encoder length
#define DIN 256   // input dim
#define HD 256    // hidden dim
#define NC 38     // classes
#define NSTEP 26  // decode steps

typedef unsigned short ushort_t;
typedef __attribute__((ext_vector_type(8))) short bf16x8;
typedef __attribute__((ext_vector_type(8))) unsigned short us8;
typedef __attribute__((ext_vector_type(4))) float f32x4;

#define GLOAD_LDS16(g, l) \
  __builtin_amdgcn_global_load_lds((const __attribute__((address_space(1))) unsigned int*)(g), \
                                   (__attribute__((address_space(3))) unsigned int*)(l), 16, 0, 0)

__device__ __forceinline__ unsigned short f2bf(float x) {
    union { float f; unsigned u; } v; v.f = x;
    unsigned r = v.u + 0x7fff + ((v.u >> 16) & 1);   // RNE
    return (unsigned short)(r >> 16);
}
__device__ __forceinline__ float bf2f(unsigned short h) {
    union { unsigned u; float f; } v; v.u = ((unsigned)h) << 16;
    return v.f;
}
__device__ __forceinline__ float fast_tanh(float x) {
    float xc = fminf(fmaxf(x, -15.f), 15.f);
    float z = __expf(2.f * xc);
    return (z - 1.f) * __builtin_amdgcn_rcpf(z + 1.f);
}
__device__ __forceinline__ float fast_sig(float x) {
    return __builtin_amdgcn_rcpf(1.f + __expf(-x));
}

// ---------------------------------------------------------------------------
// prep_all: 3584 blocks (proven in round 9).
//   [0,1024):    B2g row bid           [hi512|lo512|hi512] of [w_ih:256 | w_hh]
//   [1024,1280): B2i row bid-1024      [hi256|lo256|hi256] of w_i2h
//   [1280,1536): w2hb row bid-1280     bf16 w_h2h
//   [1536,3584): encA2 16 rows each    [hi256|lo256] of enc
// ---------------------------------------------------------------------------
__global__ __launch_bounds__(256) void prep_all(
    const float* __restrict__ w_ih, const float* __restrict__ w_hh,
    const float* __restrict__ w_i2h, const float* __restrict__ w_h2h,
    const float* __restrict__ enc,
    ushort_t* __restrict__ B2g, ushort_t* __restrict__ B2i,
    ushort_t* __restrict__ w2hb, ushort_t* __restrict__ encA2)
{
    const int bid = blockIdx.x, tid = threadIdx.x;
    if (bid < 1024) {
        int j = bid;
        for (int k = tid; k < 512; k += 256) {
            float x = (k < 256) ? w_ih[(size_t)j * 294 + k] : w_hh[(size_t)j * 256 + (k - 256)];
            unsigned short hi = f2bf(x);
            unsigned short lo = f2bf(x - bf2f(hi));
            size_t r = (size_t)j * 1536;
            B2g[r + k] = hi; B2g[r + 512 + k] = lo; B2g[r + 1024 + k] = hi;
        }
    } else if (bid < 1280) {
        int n = bid - 1024;
        float x = w_i2h[(size_t)n * 256 + tid];
        unsigned short hi = f2bf(x);
        unsigned short lo = f2bf(x - bf2f(hi));
        size_t r = (size_t)n * 768;
        B2i[r + tid] = hi; B2i[r + 256 + tid] = lo; B2i[r + 512 + tid] = hi;
    } else if (bid < 1536) {
        int j = bid - 1280;
        w2hb[(size_t)j * 256 + tid] = f2bf(w_h2h[(size_t)j * 256 + tid]);
    } else {
        int base = (bid - 1536) * 16;
#pragma unroll
        for (int rr = 0; rr < 16; rr++) {
            size_t row = base + rr;
            float x = enc[row * 256 + tid];
            unsigned short hi = f2bf(x);
            unsigned short lo = f2bf(x - bf2f(hi));
            encA2[row * 512 + tid] = hi;
            encA2[row * 512 + 256 + tid] = lo;
        }
    }
}

// ---------------------------------------------------------------------------
// hproj_pipe: Hb[m][n] = bf16( sum_k enc[m][k]*w_i2h[n][k] )   (proven)
// ---------------------------------------------------------------------------
__global__ __launch_bounds__(256) void hproj_pipe(
    const ushort_t* __restrict__ encA2, const ushort_t* __restrict__ B2i,
    ushort_t* __restrict__ Hb)
{
    __shared__ ushort_t lA[2][64 * 128];
    __shared__ ushort_t lB[2][64 * 128];

    const int tid = threadIdx.x;
    const int lane = tid & 63, wid = tid >> 6;
    const int wm = wid >> 1, wn = wid & 1;
    const int m0 = blockIdx.x * 64, n0 = blockIdx.y * 64;

    f32x4 acc[2][2];
    const f32x4 fz = {0.f, 0.f, 0.f, 0.f};
    acc[0][0] = fz; acc[0][1] = fz; acc[1][0] = fz; acc[1][1] = fz;

    auto stage = [&](int t, int buf) {
#pragma unroll
        for (int i = 0; i < 4; i++) {
            int cpos = tid + i * 256;
            int m = cpos >> 4, p = cpos & 15;
            int g = p ^ (m & 7);
            int vk = t * 128 + g * 8;
            int acol = (vk < 256) ? vk : vk - 256;
            GLOAD_LDS16(&encA2[(size_t)(m0 + m) * 512 + acol], &lA[buf][cpos * 8]);
        }
#pragma unroll
        for (int i = 0; i < 4; i++) {
            int cpos = tid + i * 256;
            int n = cpos >> 4, p = cpos & 15;
            int g = p ^ (n & 7);
            GLOAD_LDS16(&B2i[(size_t)(n0 + n) * 768 + t * 128 + g * 8], &lB[buf][cpos * 8]);
        }
    };

    stage(0, 0);
    stage(1, 1);

    for (int t = 0; t < 6; t++) {
        int cur = t & 1;
        if (t < 5) asm volatile("s_waitcnt vmcnt(8)" ::: "memory");
        else       asm volatile("s_waitcnt vmcnt(0)" ::: "memory");
        __syncthreads();
#pragma unroll
        for (int kk = 0; kk < 4; kk++) {
            int g = kk * 4 + (lane >> 4);
            bf16x8 af[2], bfr[2];
#pragma unroll
            for (int mi = 0; mi < 2; mi++) {
                int m = wm * 32 + mi * 16 + (lane & 15);
                af[mi] = *(const bf16x8*)&lA[cur][m * 128 + ((g ^ (m & 7)) << 3)];
            }
#pragma unroll
            for (int ni = 0; ni < 2; ni++) {
                int n = wn * 32 + ni * 16 + (lane & 15);
                bfr[ni] = *(const bf16x8*)&lB[cur][n * 128 + ((g ^ (n & 7)) << 3)];
            }
#pragma unroll
            for (int mi = 0; mi < 2; mi++)
#pragma unroll
                for (int ni = 0; ni < 2; ni++)
                    acc[mi][ni] = __builtin_amdgcn_mfma_f32_16x16x32_bf16(af[mi], bfr[ni], acc[mi][ni], 0, 0, 0);
        }
        __syncthreads();
        if (t + 2 < 6) stage(t + 2, cur);
    }

    const int r4 = (lane >> 4) * 4;
#pragma unroll
    for (int mi = 0; mi < 2; mi++)
#pragma unroll
        for (int r = 0; r < 4; r++) {
            size_t row = m0 + wm * 32 + mi * 16 + r4 + r;
#pragma unroll
            for (int ni = 0; ni < 2; ni++) {
                int col = n0 + wn * 32 + ni * 16 + (lane & 15);
                Hb[row * 256 + col] = f2bf(acc[mi][ni][r]);
            }
        }
}

// ---------------------------------------------------------------------------
// gates_pipe: XCD-pinned 1D grid (256 blocks).  (verbatim round 7, proven)
// ---------------------------------------------------------------------------
__global__ __launch_bounds__(256) void gates_pipe(
    const ushort_t* __restrict__ A2, const ushort_t* __restrict__ B2,
    const float* __restrict__ b_ih, const float* __restrict__ b_hh,
    const float* __restrict__ w_ih, const int* __restrict__ text,
    int step, float* __restrict__ gates)
{
    __shared__ ushort_t lA[2][64 * 128];
    __shared__ ushort_t lB[2][64 * 128];

    const int tid = threadIdx.x;
    const int bid = blockIdx.x;
    const int xcd = bid & 7, j = bid >> 3;
    const int m0 = (j >> 1) * 64;
    const int n0 = (xcd * 2 + (j & 1)) * 64;
    const int lane = tid & 63, wid = tid >> 6;
    const int wm = wid >> 1, wn = wid & 1;

    f32x4 acc[2][2];
    const f32x4 fz = {0.f, 0.f, 0.f, 0.f};
    acc[0][0] = fz; acc[0][1] = fz; acc[1][0] = fz; acc[1][1] = fz;

    auto stage = [&](int t, int buf) {
#pragma unroll
        for (int i = 0; i < 4; i++) {
            int cpos = tid + i * 256;
            int m = cpos >> 4, p = cpos & 15;
            int g = p ^ (m & 7);
            int vk = t * 128 + g * 8;
            int acol = (vk < 512) ? vk : vk - 512;
            GLOAD_LDS16(&A2[(size_t)(m0 + m) * 1024 + acol], &lA[buf][cpos * 8]);
        }
#pragma unroll
        for (int i = 0; i < 4; i++) {
            int cpos = tid + i * 256;
            int n = cpos >> 4, p = cpos & 15;
            int g = p ^ (n & 7);
            GLOAD_LDS16(&B2[(size_t)(n0 + n) * 1536 + t * 128 + g * 8], &lB[buf][cpos * 8]);
        }
    };

    stage(0, 0);
    stage(1, 1);

    for (int t = 0; t < 12; t++) {
        int cur = t & 1;
        if (t < 11) asm volatile("s_waitcnt vmcnt(8)" ::: "memory");
        else        asm volatile("s_waitcnt vmcnt(0)" ::: "memory");
        __syncthreads();
#pragma unroll
        for (int kk = 0; kk < 4; kk++) {
            int g = kk * 4 + (lane >> 4);
            bf16x8 af[2], bfr[2];
#pragma unroll
            for (int mi = 0; mi < 2; mi++) {
                int m = wm * 32 + mi * 16 + (lane & 15);
                af[mi] = *(const bf16x8*)&lA[cur][m * 128 + ((g ^ (m & 7)) << 3)];
            }
#pragma unroll
            for (int ni = 0; ni < 2; ni++) {
                int n = wn * 32 + ni * 16 + (lane & 15);
                bfr[ni] = *(const bf16x8*)&lB[cur][n * 128 + ((g ^ (n & 7)) << 3)];
            }
#pragma unroll
            for (int mi = 0; mi < 2; mi++)
#pragma unroll
                for (int ni = 0; ni < 2; ni++)
                    acc[mi][ni] = __builtin_amdgcn_mfma_f32_16x16x32_bf16(af[mi], bfr[ni], acc[mi][ni], 0, 0, 0);
        }
        __syncthreads();
        if (t + 2 < 12) stage(t + 2, cur);
    }

    const int r4 = (lane >> 4) * 4;
#pragma unroll
    for (int mi = 0; mi < 2; mi++)
#pragma unroll
        for (int r = 0; r < 4; r++) {
            int row = m0 + wm * 32 + mi * 16 + r4 + r;
            int cl = text[row * NSTEP + step];
#pragma unroll
            for (int ni = 0; ni < 2; ni++) {
                int col = n0 + wn * 32 + ni * 16 + (lane & 15);
                float v = acc[mi][ni][r] + b_ih[col] + b_hh[col]
                        + w_ih[(size_t)col * 294 + 256 + cl];
                gates[(size_t)row * 1024 + col] = v;
            }
        }
}

// ---------------------------------------------------------------------------
// attn_step: LSTM(s-1) + probs(s-1) + hp + scores + softmax + ctx + A2.
// 1024 blocks x 256 threads, one row/block, XCD-pinned.
// Hb + enc slices PREFETCHED into registers at kernel start so the 32 MB/step
// stream overlaps the LSTM->probs->hp critical chain (T14 issue-early).
// ---------------------------------------------------------------------------
__global__ __launch_bounds__(256) void attn_step(
    const float* __restrict__ gates,
    const ushort_t* __restrict__ w2hb, const float* __restrict__ b_h2h,
    const float* __restrict__ w_gen, const float* __restrict__ b_gen,
    const float* __restrict__ w_score,
    const ushort_t* __restrict__ encA2, const ushort_t* __restrict__ Hb,
    float* __restrict__ c, ushort_t* __restrict__ A2,
    float* __restrict__ probs, int step)
{
    __shared__ float hsh[HD];
    __shared__ float hpsh[HD];
    __shared__ float wssh[HD];
    __shared__ float esh[TT];
    __shared__ float psh[8][HD + 1];

    const int tid = threadIdx.x;
    const int bid = blockIdx.x;
    const int b = (bid & 7) * 128 + (bid >> 3);

    // ---- prefetch register slices (no dependencies -> issue immediately) ----
    us8 hb0, hb1, hb2, hb3, eb0, eb1, eb2, eb3;
    if (step < NSTEP) {
        // scores mapping: t = tid>>3, sl = tid&7 holds d = sl*8 + jj*64
        const ushort_t* hr = &Hb[((size_t)b * TT + (tid >> 3)) * HD + (tid & 7) * 8];
        hb0 = *(const us8*)&hr[0];
        hb1 = *(const us8*)&hr[64];
        hb2 = *(const us8*)&hr[128];
        hb3 = *(const us8*)&hr[192];
        // ctx mapping: gq = tid>>5 covers t = gq*4+tt, l = tid&31 holds d = l*8..+8
        // bf16 hi-part of enc straight from encA2 (stride 512/row).
        const ushort_t* er = &encA2[((size_t)b * TT + (tid >> 5) * 4) * 512 + (tid & 31) * 8];
        eb0 = *(const us8*)&er[0];
        eb1 = *(const us8*)&er[512];
        eb2 = *(const us8*)&er[1024];
        eb3 = *(const us8*)&er[1536];
    }

    wssh[tid] = w_score[tid];

    if (step > 0) {
        // LSTM(step-1): one element per thread
        const float* g = &gates[(size_t)b * 1024];
        float gi = g[tid];
        float gf = g[256 + tid];
        float gg = g[512 + tid];
        float go = g[768 + tid];
        float cv = c[(size_t)b * HD + tid];
        float cn = fast_sig(gf) * cv + fast_sig(gi) * fast_tanh(gg);
        float hn = fast_sig(go) * fast_tanh(cn);
        c[(size_t)b * HD + tid] = cn;
        hsh[tid] = hn;
        if (step < NSTEP) {
            unsigned short hi_ = f2bf(hn);
            A2[(size_t)b * 1024 + 256 + tid] = hi_;
            A2[(size_t)b * 1024 + 768 + tid] = f2bf(hn - bf2f(hi_));
        }
        __syncthreads();
        // probs(step-1): 4 threads per class j, 64 d each
        if (tid < 4 * NC) {
            int jj = tid >> 2, q = tid & 3;
            const float* wg = &w_gen[(size_t)jj * HD + q * 64];
            const float* hv = &hsh[q * 64];
            float s = 0.f;
#pragma unroll
            for (int d = 0; d < 64; d += 4) {
                float4 wv = *(const float4*)&wg[d];
                float4 hq = *(const float4*)&hv[d];
                s += wv.x * hq.x + wv.y * hq.y + wv.z * hq.z + wv.w * hq.w;
            }
            s += __shfl_xor(s, 1);
            s += __shfl_xor(s, 2);
            if (q == 0)
                probs[((size_t)b * NSTEP + (step - 1)) * NC + jj] = s + b_gen[jj];
        }
    } else {
        // step 0: h = c = 0
        hsh[tid] = 0.f;
        c[(size_t)b * HD + tid] = 0.f;
        A2[(size_t)b * 1024 + 256 + tid] = 0;
        A2[(size_t)b * 1024 + 768 + tid] = 0;
        __syncthreads();
    }
    if (step >= NSTEP) return;

    // hp[j] = dot(w2hb[j], h) + b_h2h[j], j = tid  (hsh reads broadcast)
    {
        float a = 0.f;
        const ushort_t* wr = &w2hb[(size_t)tid * HD];
#pragma unroll 4
        for (int d = 0; d < HD; d += 8) {
            us8 wv = *(const us8*)&wr[d];
#pragma unroll
            for (int k = 0; k < 8; k++)
                a += bf2f(wv[k]) * hsh[d + k];
        }
        hpsh[tid] = a + b_h2h[tid];
    }
    __syncthreads();

    // scores from register Hb slice: 8 threads per t, 32 d each
    {
        int sl = tid & 7;
        float e = 0.f;
#define DOT8(hbv, base) { us8 hv_ = hbv; \
  _Pragma("unroll") for (int k = 0; k < 8; k++) { int d_ = (base) + k; \
      e += wssh[d_] * fast_tanh(bf2f(hv_[k]) + hpsh[d_]); } }
        DOT8(hb0, sl * 8)
        DOT8(hb1, sl * 8 + 64)
        DOT8(hb2, sl * 8 + 128)
        DOT8(hb3, sl * 8 + 192)
#undef DOT8
        e += __shfl_xor(e, 4);
        e += __shfl_xor(e, 2);
        e += __shfl_xor(e, 1);
        if (sl == 0) esh[tid >> 3] = e;
    }
    __syncthreads();

    // softmax over 32 t
    if (tid < 32) {
        float v = esh[tid];
        float m = v;
#pragma unroll
        for (int o = 16; o > 0; o >>= 1) m = fmaxf(m, __shfl_xor(m, o));
        float p = __expf(v - m);
        float ssum = p;
#pragma unroll
        for (int o = 16; o > 0; o >>= 1) ssum += __shfl_xor(ssum, o);
        esh[tid] = p * __builtin_amdgcn_rcpf(ssum);
    }
    __syncthreads();

    // context from register enc slice
    {
        int gq = tid >> 5;
        float pp[8] = {0.f, 0.f, 0.f, 0.f, 0.f, 0.f, 0.f, 0.f};
#define CTXACC(ebv, tt) { float a_ = esh[gq * 4 + (tt)]; us8 ev_ = ebv; \
  _Pragma("unroll") for (int k = 0; k < 8; k++) pp[k] += a_ * bf2f(ev_[k]); }
        CTXACC(eb0, 0) CTXACC(eb1, 1) CTXACC(eb2, 2) CTXACC(eb3, 3)
#undef CTXACC
        int l = tid & 31;
#pragma unroll
        for (int k = 0; k < 8; k++)
            psh[gq][l * 8 + k] = pp[k];
    }
    __syncthreads();
    {
        float a = 0.f;
#pragma unroll
        for (int gq = 0; gq < 8; gq++)
            a += psh[gq][tid];
        unsigned short hi_ = f2bf(a);
        A2[(size_t)b * 1024 + tid] = hi_;
        A2[(size_t)b * 1024 + 512 + tid] = f2bf(a - bf2f(hi_));
    }
}

// ---------------------------------------------------------------------------
extern "C" void kernel_launch(void* const* d_in, const int* in_sizes, int n_in,
                              void* d_out, int out_size, void* d_ws, size_t ws_size,
                              hipStream_t stream)
{
    const float* enc     = (const float*)d_in[0];
    const int*   text    = (const int*)d_in[1];
    const float* w_i2h   = (const float*)d_in[4];
    const float* w_h2h   = (const float*)d_in[5];
    const float* b_h2h   = (const float*)d_in[6];
    const float* w_score = (const float*)d_in[7];
    const float* w_ih    = (const float*)d_in[8];
    const float* w_hh    = (const float*)d_in[9];
    const float* b_ih    = (const float*)d_in[10];
    const float* b_hh    = (const float*)d_in[11];
    const float* w_gen   = (const float*)d_in[12];
    const float* b_gen   = (const float*)d_in[13];
    float* out = (float*)d_out;

    const size_t MB = 1024 * 1024;
    char* ws = (char*)d_ws;
    ushort_t* Hb    = (ushort_t*)ws;                          // 16 MB  [0,16)
    ushort_t* B2g   = (ushort_t*)(ws + 16 * MB);              // 3 MB   [16,19)
    ushort_t* B2i   = (ushort_t*)(ws + 19 * MB);              // 384 KB
    ushort_t* w2hb  = (ushort_t*)(ws + 19 * MB + 512 * 1024); // 128 KB
    float*    cbuf  = (float*)(ws + 20 * MB);                 // 1 MB   [20,21)
    ushort_t* A2    = (ushort_t*)(ws + 21 * MB);              // 2 MB   [21,23)
    float*    gates = (float*)(ws + 23 * MB);                 // 4 MB   [23,27)
    ushort_t* encA2 = (ushort_t*)(ws + 27 * MB);              // 32 MB  [27,59)

    prep_all<<<3584, 256, 0, stream>>>(w_ih, w_hh, w_i2h, w_h2h, enc,
                                       B2g, B2i, w2hb, encA2);
    hproj_pipe<<<dim3(512, 4), 256, 0, stream>>>(encA2, B2i, Hb);

    for (int s = 0; s < NSTEP; s++) {
        attn_step<<<1024, 256, 0, stream>>>(gates, w2hb, b_h2h, w_gen, b_gen,
                                            w_score, encA2, Hb, cbuf, A2, out, s);
        gates_pipe<<<256, 256, 0, stream>>>(A2, B2g, b_ih, b_hh,
                                            w_ih, text, s, gates);
    }
    attn_step<<<1024, 256, 0, stream>>>(gates, w2hb, b_h2h, w_gen, b_gen,
                                        w_score, encA2, Hb, cbuf, A2, out, NSTEP);
}